// Round 1
// baseline (1373.659 us; speedup 1.0000x reference)
//
#include <hip/hip_runtime.h>
#include <math.h>

#define B_   64
#define N_   196
#define VD_  512
#define ED_  512
#define HD_  512
#define V_   10000
#define T_   20
#define G4_  2048   // 4*HD

static __device__ __forceinline__ float sigmoidf_(float x) {
  return 1.f / (1.f + __expf(-x));
}

// ---------------------------------------------------------------------------
// K1: per-batch attention logits (f·W_av), softmax over n, ctx, and feature
// mean (for h0/c0). att_h/b_av/b_ah cancel in softmax over n -> ignored.
// grid: 64 blocks (one per b), 256 threads.
// ---------------------------------------------------------------------------
__global__ void k_attn_ctx(const float* __restrict__ feat,
                           const float* __restrict__ W_av,
                           float* __restrict__ fmean,
                           float* __restrict__ ctx) {
  __shared__ float sv[N_];
  __shared__ float red[8];
  int b = blockIdx.x, t = threadIdx.x;
  int lane = t & 63, wid = t >> 6;
  const float* fb = feat + (size_t)b * (N_ * VD_);
  float wa0 = W_av[t], wa1 = W_av[t + 256];
  float fs0 = 0.f, fs1 = 0.f;

  for (int n = 0; n < N_; ++n) {
    float f0 = fb[n * VD_ + t], f1 = fb[n * VD_ + t + 256];
    fs0 += f0; fs1 += f1;
    float p = f0 * wa0 + f1 * wa1;
#pragma unroll
    for (int off = 32; off > 0; off >>= 1) p += __shfl_down(p, off, 64);
    if (lane == 0) red[wid] = p;
    __syncthreads();
    if (t == 0) sv[n] = red[0] + red[1] + red[2] + red[3];
    __syncthreads();
  }

  // softmax over sv[0..195]
  float m = -1e30f;
  for (int n = t; n < N_; n += 256) m = fmaxf(m, sv[n]);
#pragma unroll
  for (int off = 32; off > 0; off >>= 1) m = fmaxf(m, __shfl_down(m, off, 64));
  if (lane == 0) red[4 + wid] = m;
  __syncthreads();
  m = fmaxf(fmaxf(red[4], red[5]), fmaxf(red[6], red[7]));

  float sl = 0.f;
  for (int n = t; n < N_; n += 256) {
    float e = __expf(sv[n] - m);
    sv[n] = e;
    sl += e;
  }
#pragma unroll
  for (int off = 32; off > 0; off >>= 1) sl += __shfl_down(sl, off, 64);
  if (lane == 0) red[wid] = sl;
  __syncthreads();   // covers sv writes AND red writes
  float inv = 1.f / (red[0] + red[1] + red[2] + red[3]);

  float c0 = 0.f, c1 = 0.f;
  for (int n = 0; n < N_; ++n) {
    float a = sv[n];
    c0 += a * fb[n * VD_ + t];
    c1 += a * fb[n * VD_ + t + 256];
  }
  ctx[b * VD_ + t]        = c0 * inv;
  ctx[b * VD_ + t + 256]  = c1 * inv;
  fmean[b * VD_ + t]       = fs0 * (1.f / N_);
  fmean[b * VD_ + t + 256] = fs1 * (1.f / N_);
}

// ---------------------------------------------------------------------------
// bsum[j] = b_ih[j] + b_hh[j]
// ---------------------------------------------------------------------------
__global__ void k_bsum(const float* __restrict__ b_ih,
                       const float* __restrict__ b_hh,
                       float* __restrict__ bsum) {
  int i = blockIdx.x * 256 + threadIdx.x;
  if (i < G4_) bsum[i] = b_ih[i] + b_hh[i];
}

// ---------------------------------------------------------------------------
// Tiled fp32 GEMM: C[M,N] = A[M,K] @ Bw[N,K]^T (+ bias[n]).
// 64x64 tile, BK=16, 256 threads, 4x4 per thread. M % 64 == 0; N edge guarded.
// ---------------------------------------------------------------------------
#define BK 16
__global__ void k_gemm_bt(const float* __restrict__ A, int lda,
                          const float* __restrict__ Bw, int ldb,
                          float* __restrict__ C, int ldc,
                          int Nn, int K,
                          const float* __restrict__ bias) {
  __shared__ float As[BK][64];
  __shared__ float Bs[BK][64];
  int m0 = blockIdx.y * 64, n0 = blockIdx.x * 64;
  int tid = threadIdx.x;
  int tm = tid & 15, tn = tid >> 4;
  int sr = tid >> 2;           // 0..63
  int sk = (tid & 3) * 4;      // 0,4,8,12
  const float* arow = A + (size_t)(m0 + sr) * lda;
  int bn = n0 + sr;
  const float* brow = Bw + (size_t)(bn < Nn ? bn : Nn - 1) * ldb;
  float acc[4][4] = {};

  for (int k0 = 0; k0 < K; k0 += BK) {
    float4 av = *(const float4*)(arow + k0 + sk);
    float4 bv = *(const float4*)(brow + k0 + sk);
    __syncthreads();
    As[sk + 0][sr] = av.x; As[sk + 1][sr] = av.y;
    As[sk + 2][sr] = av.z; As[sk + 3][sr] = av.w;
    Bs[sk + 0][sr] = bv.x; Bs[sk + 1][sr] = bv.y;
    Bs[sk + 2][sr] = bv.z; Bs[sk + 3][sr] = bv.w;
    __syncthreads();
#pragma unroll
    for (int kk = 0; kk < BK; ++kk) {
      float4 a4 = *(const float4*)&As[kk][tm * 4];
      float4 b4 = *(const float4*)&Bs[kk][tn * 4];
      acc[0][0] += a4.x * b4.x; acc[0][1] += a4.x * b4.y; acc[0][2] += a4.x * b4.z; acc[0][3] += a4.x * b4.w;
      acc[1][0] += a4.y * b4.x; acc[1][1] += a4.y * b4.y; acc[1][2] += a4.y * b4.z; acc[1][3] += a4.y * b4.w;
      acc[2][0] += a4.z * b4.x; acc[2][1] += a4.z * b4.y; acc[2][2] += a4.z * b4.z; acc[2][3] += a4.z * b4.w;
      acc[3][0] += a4.w * b4.x; acc[3][1] += a4.w * b4.y; acc[3][2] += a4.w * b4.z; acc[3][3] += a4.w * b4.w;
    }
  }
#pragma unroll
  for (int j = 0; j < 4; ++j) {
    int n = n0 + tn * 4 + j;
    if (n < Nn) {
      float bb = bias ? bias[n] : 0.f;
#pragma unroll
      for (int i = 0; i < 4; ++i) {
        int m = m0 + tm * 4 + i;
        C[(size_t)m * ldc + n] = acc[i][j] + bb;
      }
    }
  }
}

// ---------------------------------------------------------------------------
// gpre[t*64+b, j] = embed[captions[b,t], :] . W_ih[j, VD:]  + gctx[b, j]
// Same tiling as k_gemm_bt, A rows gathered from the embedding table.
// ---------------------------------------------------------------------------
__global__ void k_gemm_emb(const float* __restrict__ embed,
                           const int* __restrict__ caps,     // [B,T]
                           const float* __restrict__ Bw, int ldb,  // W_ih+VD, ldb=1024
                           const float* __restrict__ gctx,   // [64][2048] incl. biases
                           float* __restrict__ C) {          // gpre [1280][2048]
  __shared__ float As[BK][64];
  __shared__ float Bs[BK][64];
  int m0 = blockIdx.y * 64, n0 = blockIdx.x * 64;
  int tid = threadIdx.x;
  int tm = tid & 15, tn = tid >> 4;
  int sr = tid >> 2;
  int sk = (tid & 3) * 4;
  int row = m0 + sr;
  int bidx = row & 63, tt = row >> 6;
  const float* arow = embed + (size_t)caps[bidx * T_ + tt] * ED_;
  const float* brow = Bw + (size_t)(n0 + sr) * ldb;
  float acc[4][4] = {};

  for (int k0 = 0; k0 < ED_; k0 += BK) {
    float4 av = *(const float4*)(arow + k0 + sk);
    float4 bv = *(const float4*)(brow + k0 + sk);
    __syncthreads();
    As[sk + 0][sr] = av.x; As[sk + 1][sr] = av.y;
    As[sk + 2][sr] = av.z; As[sk + 3][sr] = av.w;
    Bs[sk + 0][sr] = bv.x; Bs[sk + 1][sr] = bv.y;
    Bs[sk + 2][sr] = bv.z; Bs[sk + 3][sr] = bv.w;
    __syncthreads();
#pragma unroll
    for (int kk = 0; kk < BK; ++kk) {
      float4 a4 = *(const float4*)&As[kk][tm * 4];
      float4 b4 = *(const float4*)&Bs[kk][tn * 4];
      acc[0][0] += a4.x * b4.x; acc[0][1] += a4.x * b4.y; acc[0][2] += a4.x * b4.z; acc[0][3] += a4.x * b4.w;
      acc[1][0] += a4.y * b4.x; acc[1][1] += a4.y * b4.y; acc[1][2] += a4.y * b4.z; acc[1][3] += a4.y * b4.w;
      acc[2][0] += a4.z * b4.x; acc[2][1] += a4.z * b4.y; acc[2][2] += a4.z * b4.z; acc[2][3] += a4.z * b4.w;
      acc[3][0] += a4.w * b4.x; acc[3][1] += a4.w * b4.y; acc[3][2] += a4.w * b4.z; acc[3][3] += a4.w * b4.w;
    }
  }
#pragma unroll
  for (int j = 0; j < 4; ++j) {
    int n = n0 + tn * 4 + j;
#pragma unroll
    for (int i = 0; i < 4; ++i) {
      int m = m0 + tm * 4 + i;
      C[(size_t)m * G4_ + n] = acc[i][j] + gctx[(size_t)(m & 63) * G4_ + n];
    }
  }
}

// ---------------------------------------------------------------------------
// One LSTM step, fused gates GEMM + cell update.
// grid 128 blocks x 256 thr; thread = (b = tid&63, lh = tid>>6); hidx = bx*4+lh.
// Computes 4 dots (i,f,g,o rows of W_hh) against h_in[b,:] staged in LDS.
// h ping-pongs via hall (no in-place h write -> no cross-block race);
// c[b,hidx] is thread-private -> in-place ok.
// ---------------------------------------------------------------------------
__global__ void k_step(const float* __restrict__ W_hh,    // [2048][512]
                       const float* __restrict__ gpre_t,  // [64][2048]
                       const float* __restrict__ h_in,    // [64][512]
                       float* __restrict__ c,             // [64][512] in/out
                       float* __restrict__ h_out) {       // [64][512]
  __shared__ float hs[64][65];   // hs[k][b], padded: conflict-free both ways
  int tid = threadIdx.x;
  int b = tid & 63, lh = tid >> 6;
  int hidx = blockIdx.x * 4 + lh;
  const float* w0 = W_hh + (size_t)(0 * HD_ + hidx) * HD_;
  const float* w1 = W_hh + (size_t)(1 * HD_ + hidx) * HD_;
  const float* w2 = W_hh + (size_t)(2 * HD_ + hidx) * HD_;
  const float* w3 = W_hh + (size_t)(3 * HD_ + hidx) * HD_;
  float acc0 = 0.f, acc1 = 0.f, acc2 = 0.f, acc3 = 0.f;

  for (int k0 = 0; k0 < HD_; k0 += 64) {
    __syncthreads();
    {
      int r = tid >> 2;            // 0..63
      int ks = (tid & 3) * 16;     // 0,16,32,48
      const float* hp = h_in + r * HD_ + k0 + ks;
      float4 v0 = *(const float4*)(hp + 0);
      float4 v1 = *(const float4*)(hp + 4);
      float4 v2 = *(const float4*)(hp + 8);
      float4 v3 = *(const float4*)(hp + 12);
      hs[ks +  0][r] = v0.x; hs[ks +  1][r] = v0.y; hs[ks +  2][r] = v0.z; hs[ks +  3][r] = v0.w;
      hs[ks +  4][r] = v1.x; hs[ks +  5][r] = v1.y; hs[ks +  6][r] = v1.z; hs[ks +  7][r] = v1.w;
      hs[ks +  8][r] = v2.x; hs[ks +  9][r] = v2.y; hs[ks + 10][r] = v2.z; hs[ks + 11][r] = v2.w;
      hs[ks + 12][r] = v3.x; hs[ks + 13][r] = v3.y; hs[ks + 14][r] = v3.z; hs[ks + 15][r] = v3.w;
    }
    __syncthreads();
#pragma unroll
    for (int kk = 0; kk < 64; kk += 4) {
      int k = k0 + kk;
      float4 a0 = *(const float4*)(w0 + k);
      float4 a1 = *(const float4*)(w1 + k);
      float4 a2 = *(const float4*)(w2 + k);
      float4 a3 = *(const float4*)(w3 + k);
      float h0v = hs[kk + 0][b], h1v = hs[kk + 1][b];
      float h2v = hs[kk + 2][b], h3v = hs[kk + 3][b];
      acc0 += h0v * a0.x + h1v * a0.y + h2v * a0.z + h3v * a0.w;
      acc1 += h0v * a1.x + h1v * a1.y + h2v * a1.z + h3v * a1.w;
      acc2 += h0v * a2.x + h1v * a2.y + h2v * a2.z + h3v * a2.w;
      acc3 += h0v * a3.x + h1v * a3.y + h2v * a3.z + h3v * a3.w;
    }
  }

  float gi = acc0 + gpre_t[(size_t)b * G4_ + 0 * HD_ + hidx];
  float gf = acc1 + gpre_t[(size_t)b * G4_ + 1 * HD_ + hidx];
  float gg = acc2 + gpre_t[(size_t)b * G4_ + 2 * HD_ + hidx];
  float go = acc3 + gpre_t[(size_t)b * G4_ + 3 * HD_ + hidx];
  float cn = sigmoidf_(gf) * c[(size_t)b * HD_ + hidx] + sigmoidf_(gi) * tanhf(gg);
  c[(size_t)b * HD_ + hidx] = cn;
  h_out[(size_t)b * HD_ + hidx] = sigmoidf_(go) * tanhf(cn);
}

// ---------------------------------------------------------------------------
// Fused log_softmax + softmax per row of logits [1280][10000].
// logits live in the softmax output slot -> overwritten in place; log_softmax
// goes to out1. Every element of both outputs written (d_out is poisoned).
// ---------------------------------------------------------------------------
__global__ void k_softmax(float* __restrict__ logits, float* __restrict__ out1) {
  __shared__ float red[8];
  int row = blockIdx.x, tid = threadIdx.x;
  int lane = tid & 63, wid = tid >> 6;
  float* lr = logits + (size_t)row * V_;
  float* o1 = out1 + (size_t)row * V_;
  const int NV4 = V_ / 4;  // 2500

  float m = -1e30f;
  for (int i = tid; i < NV4; i += 256) {
    float4 v = ((const float4*)lr)[i];
    m = fmaxf(m, fmaxf(fmaxf(v.x, v.y), fmaxf(v.z, v.w)));
  }
#pragma unroll
  for (int off = 32; off > 0; off >>= 1) m = fmaxf(m, __shfl_down(m, off, 64));
  if (lane == 0) red[4 + wid] = m;
  __syncthreads();
  m = fmaxf(fmaxf(red[4], red[5]), fmaxf(red[6], red[7]));

  float s = 0.f;
  for (int i = tid; i < NV4; i += 256) {
    float4 v = ((const float4*)lr)[i];
    s += __expf(v.x - m) + __expf(v.y - m) + __expf(v.z - m) + __expf(v.w - m);
  }
#pragma unroll
  for (int off = 32; off > 0; off >>= 1) s += __shfl_down(s, off, 64);
  if (lane == 0) red[wid] = s;
  __syncthreads();
  s = red[0] + red[1] + red[2] + red[3];
  float ls = __logf(s), inv = 1.f / s;

  for (int i = tid; i < NV4; i += 256) {
    float4 v = ((const float4*)lr)[i];
    float4 a, bb;
    a.x = v.x - m - ls; a.y = v.y - m - ls; a.z = v.z - m - ls; a.w = v.w - m - ls;
    bb.x = __expf(v.x - m) * inv; bb.y = __expf(v.y - m) * inv;
    bb.z = __expf(v.z - m) * inv; bb.w = __expf(v.w - m) * inv;
    ((float4*)o1)[i] = a;
    ((float4*)lr)[i] = bb;
  }
}

// ---------------------------------------------------------------------------
extern "C" void kernel_launch(void* const* d_in, const int* in_sizes, int n_in,
                              void* d_out, int out_size, void* d_ws, size_t ws_size,
                              hipStream_t stream) {
  const float* features = (const float*)d_in[0];
  const int*   captions = (const int*)d_in[1];
  const float* W_init_h = (const float*)d_in[2];
  const float* W_init_c = (const float*)d_in[3];
  const float* W_av     = (const float*)d_in[4];
  // d_in[5] b_av, d_in[6] W_ah, d_in[7] b_ah: cancel inside softmax over n.
  const float* embed    = (const float*)d_in[8];
  const float* W_ih     = (const float*)d_in[9];
  const float* W_hh     = (const float*)d_in[10];
  const float* b_ih     = (const float*)d_in[11];
  const float* b_hh     = (const float*)d_in[12];
  const float* W_out    = (const float*)d_in[13];
  const float* b_out    = (const float*)d_in[14];

  float* ws    = (float*)d_ws;
  float* fmean = ws;                       // 64*512
  float* ctx   = fmean + B_ * VD_;         // 64*512
  float* hbuf  = ctx + B_ * VD_;           // 64*512  (h0)
  float* cbuf  = hbuf + B_ * HD_;          // 64*512  (c, in-place)
  float* gctx  = cbuf + B_ * HD_;          // 64*2048 (ctx@W_ihc^T + b_ih + b_hh)
  float* bsum  = gctx + (size_t)B_ * G4_;  // 2048
  float* gpre  = bsum + G4_;               // 20*64*2048
  float* hall  = gpre + (size_t)T_ * B_ * G4_;  // 20*64*512
  // total ws: ~3.54M floats = 14.2 MB

  float* out1   = (float*)d_out;                      // log_softmax [T,B,V]
  float* logits = out1 + (size_t)T_ * B_ * V_;        // softmax slot = logits scratch

  k_attn_ctx<<<B_, 256, 0, stream>>>(features, W_av, fmean, ctx);
  k_bsum<<<G4_ / 256, 256, 0, stream>>>(b_ih, b_hh, bsum);

  // h0 = fmean @ W_init_h^T ; c0 = fmean @ W_init_c^T
  k_gemm_bt<<<dim3(HD_ / 64, B_ / 64), 256, 0, stream>>>(
      fmean, VD_, W_init_h, VD_, hbuf, HD_, HD_, VD_, nullptr);
  k_gemm_bt<<<dim3(HD_ / 64, B_ / 64), 256, 0, stream>>>(
      fmean, VD_, W_init_c, VD_, cbuf, HD_, HD_, VD_, nullptr);

  // gctx = ctx @ W_ih[:, :VD]^T + (b_ih + b_hh)
  k_gemm_bt<<<dim3(G4_ / 64, B_ / 64), 256, 0, stream>>>(
      ctx, VD_, W_ih, VD_ + ED_, gctx, G4_, G4_, VD_, bsum);

  // gpre[t*64+b, :] = embed[captions[b,t]] @ W_ih[:, VD:]^T + gctx[b, :]
  k_gemm_emb<<<dim3(G4_ / 64, (T_ * B_) / 64), 256, 0, stream>>>(
      embed, captions, W_ih + VD_, VD_ + ED_, gctx, gpre);

  // sequential LSTM
  for (int t = 0; t < T_; ++t) {
    const float* h_in = (t == 0) ? hbuf : (hall + (size_t)(t - 1) * B_ * HD_);
    k_step<<<HD_ / 4, 256, 0, stream>>>(
        W_hh, gpre + (size_t)t * B_ * G4_, h_in, cbuf, hall + (size_t)t * B_ * HD_);
  }

  // logits = hall @ W_out^T + b_out   (dominant GEMM: 1280x10000x512)
  k_gemm_bt<<<dim3((V_ + 63) / 64, (T_ * B_) / 64), 256, 0, stream>>>(
      hall, HD_, W_out, HD_, logits, V_, V_, HD_, b_out);

  // out1 = log_softmax, logits slot overwritten with softmax
  k_softmax<<<T_ * B_, 256, 0, stream>>>(logits, out1);
}

// Round 2
// 827.553 us; speedup vs baseline: 1.6599x; 1.6599x over previous
//
#include <hip/hip_runtime.h>
#include <math.h>

#define B_   64
#define N_   196
#define VD_  512
#define ED_  512
#define HD_  512
#define V_   10000
#define T_   20
#define G4_  2048   // 4*HD

typedef __attribute__((ext_vector_type(8))) short bf16x8;
typedef __attribute__((ext_vector_type(4))) float f32x4;

static __device__ __forceinline__ float sigmoidf_(float x) {
  return 1.f / (1.f + __expf(-x));
}

static __device__ __forceinline__ unsigned short f2bf_(float x) {
  unsigned u = __float_as_uint(x);
  unsigned r = (u + 0x7FFFu + ((u >> 16) & 1u)) >> 16;   // RNE
  return (unsigned short)r;
}

// ---------------------------------------------------------------------------
// K1: attention logits (f·W_av), softmax over n, ctx, feature mean.
// att_h/b_av/b_ah cancel in softmax over n -> ignored.
// grid 64 (one per b) x 256. Pass 1: each wave owns n strided by 4, lane
// covers 8 dims -> shuffle-reduce only, no block barrier in the loop.
// ---------------------------------------------------------------------------
__global__ void k_attn_ctx(const float* __restrict__ feat,
                           const float* __restrict__ W_av,
                           float* __restrict__ fmean,
                           float* __restrict__ ctx) {
  __shared__ float sv[N_];
  __shared__ float red[8];
  int b = blockIdx.x, tid = threadIdx.x;
  int lane = tid & 63, w = tid >> 6;
  const float* fb = feat + (size_t)b * (N_ * VD_);
  float4 wv0 = *(const float4*)(W_av + lane * 8);
  float4 wv1 = *(const float4*)(W_av + lane * 8 + 4);

  for (int n = w; n < N_; n += 4) {
    const float* fp = fb + n * VD_ + lane * 8;
    float4 f0 = *(const float4*)fp;
    float4 f1 = *(const float4*)(fp + 4);
    float p = f0.x * wv0.x + f0.y * wv0.y + f0.z * wv0.z + f0.w * wv0.w
            + f1.x * wv1.x + f1.y * wv1.y + f1.z * wv1.z + f1.w * wv1.w;
#pragma unroll
    for (int off = 32; off > 0; off >>= 1) p += __shfl_down(p, off, 64);
    if (lane == 0) sv[n] = p;
  }
  __syncthreads();

  // softmax over sv[0..195]
  float m = -1e30f;
  for (int n = tid; n < N_; n += 256) m = fmaxf(m, sv[n]);
#pragma unroll
  for (int off = 32; off > 0; off >>= 1) m = fmaxf(m, __shfl_down(m, off, 64));
  if (lane == 0) red[4 + w] = m;
  __syncthreads();
  m = fmaxf(fmaxf(red[4], red[5]), fmaxf(red[6], red[7]));

  float sl = 0.f;
  for (int n = tid; n < N_; n += 256) {
    float e = __expf(sv[n] - m);
    sv[n] = e;
    sl += e;
  }
#pragma unroll
  for (int off = 32; off > 0; off >>= 1) sl += __shfl_down(sl, off, 64);
  if (lane == 0) red[w] = sl;
  __syncthreads();   // covers sv writes AND red writes
  float inv = 1.f / (red[0] + red[1] + red[2] + red[3]);

  // pass 2: ctx + fmean, coalesced (thread covers dims tid and tid+256)
  float c0 = 0.f, c1 = 0.f, fs0 = 0.f, fs1 = 0.f;
  for (int n = 0; n < N_; ++n) {
    float a = sv[n];
    float f0 = fb[n * VD_ + tid], f1 = fb[n * VD_ + tid + 256];
    c0 += a * f0; c1 += a * f1;
    fs0 += f0;    fs1 += f1;
  }
  ctx[b * VD_ + tid]        = c0 * inv;
  ctx[b * VD_ + tid + 256]  = c1 * inv;
  fmean[b * VD_ + tid]       = fs0 * (1.f / N_);
  fmean[b * VD_ + tid + 256] = fs1 * (1.f / N_);
}

// ---------------------------------------------------------------------------
__global__ void k_bsum(const float* __restrict__ b_ih,
                       const float* __restrict__ b_hh,
                       float* __restrict__ bsum) {
  int i = blockIdx.x * 256 + threadIdx.x;
  if (i < G4_) bsum[i] = b_ih[i] + b_hh[i];
}

// ---------------------------------------------------------------------------
// fp32 -> bf16 cast, 4 elems/thread. n4 = n/4 (n % 4 == 0).
// ---------------------------------------------------------------------------
__global__ void k_cast4(const float* __restrict__ s, unsigned short* __restrict__ d, int n4) {
  int i = blockIdx.x * 256 + threadIdx.x;
  if (i < n4) {
    float4 v = ((const float4*)s)[i];
    ushort4 o;
    o.x = f2bf_(v.x); o.y = f2bf_(v.y); o.z = f2bf_(v.z); o.w = f2bf_(v.w);
    ((ushort4*)d)[i] = o;
  }
}

// ---------------------------------------------------------------------------
// Tiled fp32 GEMM: C[M,N] = A[M,K] @ Bw[N,K]^T (+ bias). 64x64 tile, BK=16.
// ---------------------------------------------------------------------------
#define BK 16
__global__ void k_gemm_bt(const float* __restrict__ A, int lda,
                          const float* __restrict__ Bw, int ldb,
                          float* __restrict__ C, int ldc,
                          int Nn, int K,
                          const float* __restrict__ bias) {
  __shared__ float As[BK][64];
  __shared__ float Bs[BK][64];
  int m0 = blockIdx.y * 64, n0 = blockIdx.x * 64;
  int tid = threadIdx.x;
  int tm = tid & 15, tn = tid >> 4;
  int sr = tid >> 2;
  int sk = (tid & 3) * 4;
  const float* arow = A + (size_t)(m0 + sr) * lda;
  int bn = n0 + sr;
  const float* brow = Bw + (size_t)(bn < Nn ? bn : Nn - 1) * ldb;
  float acc[4][4] = {};

  for (int k0 = 0; k0 < K; k0 += BK) {
    float4 av = *(const float4*)(arow + k0 + sk);
    float4 bv = *(const float4*)(brow + k0 + sk);
    __syncthreads();
    As[sk + 0][sr] = av.x; As[sk + 1][sr] = av.y;
    As[sk + 2][sr] = av.z; As[sk + 3][sr] = av.w;
    Bs[sk + 0][sr] = bv.x; Bs[sk + 1][sr] = bv.y;
    Bs[sk + 2][sr] = bv.z; Bs[sk + 3][sr] = bv.w;
    __syncthreads();
#pragma unroll
    for (int kk = 0; kk < BK; ++kk) {
      float4 a4 = *(const float4*)&As[kk][tm * 4];
      float4 b4 = *(const float4*)&Bs[kk][tn * 4];
      acc[0][0] += a4.x * b4.x; acc[0][1] += a4.x * b4.y; acc[0][2] += a4.x * b4.z; acc[0][3] += a4.x * b4.w;
      acc[1][0] += a4.y * b4.x; acc[1][1] += a4.y * b4.y; acc[1][2] += a4.y * b4.z; acc[1][3] += a4.y * b4.w;
      acc[2][0] += a4.z * b4.x; acc[2][1] += a4.z * b4.y; acc[2][2] += a4.z * b4.z; acc[2][3] += a4.z * b4.w;
      acc[3][0] += a4.w * b4.x; acc[3][1] += a4.w * b4.y; acc[3][2] += a4.w * b4.z; acc[3][3] += a4.w * b4.w;
    }
  }
#pragma unroll
  for (int j = 0; j < 4; ++j) {
    int n = n0 + tn * 4 + j;
    if (n < Nn) {
      float bb = bias ? bias[n] : 0.f;
#pragma unroll
      for (int i = 0; i < 4; ++i) {
        int m = m0 + tm * 4 + i;
        C[(size_t)m * ldc + n] = acc[i][j] + bb;
      }
    }
  }
}

// ---------------------------------------------------------------------------
// gpre[t*64+b, j] = embed[captions[b,t], :] . W_ih[j, VD:]  + gctx[b, j]
// ---------------------------------------------------------------------------
__global__ void k_gemm_emb(const float* __restrict__ embed,
                           const int* __restrict__ caps,
                           const float* __restrict__ Bw, int ldb,
                           const float* __restrict__ gctx,
                           float* __restrict__ C) {
  __shared__ float As[BK][64];
  __shared__ float Bs[BK][64];
  int m0 = blockIdx.y * 64, n0 = blockIdx.x * 64;
  int tid = threadIdx.x;
  int tm = tid & 15, tn = tid >> 4;
  int sr = tid >> 2;
  int sk = (tid & 3) * 4;
  int row = m0 + sr;
  int bidx = row & 63, tt = row >> 6;
  const float* arow = embed + (size_t)caps[bidx * T_ + tt] * ED_;
  const float* brow = Bw + (size_t)(n0 + sr) * ldb;
  float acc[4][4] = {};

  for (int k0 = 0; k0 < ED_; k0 += BK) {
    float4 av = *(const float4*)(arow + k0 + sk);
    float4 bv = *(const float4*)(brow + k0 + sk);
    __syncthreads();
    As[sk + 0][sr] = av.x; As[sk + 1][sr] = av.y;
    As[sk + 2][sr] = av.z; As[sk + 3][sr] = av.w;
    Bs[sk + 0][sr] = bv.x; Bs[sk + 1][sr] = bv.y;
    Bs[sk + 2][sr] = bv.z; Bs[sk + 3][sr] = bv.w;
    __syncthreads();
#pragma unroll
    for (int kk = 0; kk < BK; ++kk) {
      float4 a4 = *(const float4*)&As[kk][tm * 4];
      float4 b4 = *(const float4*)&Bs[kk][tn * 4];
      acc[0][0] += a4.x * b4.x; acc[0][1] += a4.x * b4.y; acc[0][2] += a4.x * b4.z; acc[0][3] += a4.x * b4.w;
      acc[1][0] += a4.y * b4.x; acc[1][1] += a4.y * b4.y; acc[1][2] += a4.y * b4.z; acc[1][3] += a4.y * b4.w;
      acc[2][0] += a4.z * b4.x; acc[2][1] += a4.z * b4.y; acc[2][2] += a4.z * b4.z; acc[2][3] += a4.z * b4.w;
      acc[3][0] += a4.w * b4.x; acc[3][1] += a4.w * b4.y; acc[3][2] += a4.w * b4.z; acc[3][3] += a4.w * b4.w;
    }
  }
#pragma unroll
  for (int j = 0; j < 4; ++j) {
    int n = n0 + tn * 4 + j;
#pragma unroll
    for (int i = 0; i < 4; ++i) {
      int m = m0 + tm * 4 + i;
      C[(size_t)m * G4_ + n] = acc[i][j] + gctx[(size_t)(m & 63) * G4_ + n];
    }
  }
}

// ---------------------------------------------------------------------------
// One LSTM step. grid 256 x 256 thr. wave w: hidx = blockIdx*2 + (w&1),
// gate-pair = w>>1 (0: i,f ; 1: g,o). Each wave does 2 dot products of
// length 512 for its hidx against h_in staged in LDS; gate-pair 1 hands
// its partials to gate-pair 0 via LDS for the cell update.
// W_hh row pointers are wave-uniform -> scalar loads.
// ---------------------------------------------------------------------------
__global__ __launch_bounds__(256) void k_step(
    const float* __restrict__ W_hh,    // [2048][512]
    const float* __restrict__ gpre_t,  // [64][2048]
    const float* __restrict__ h_in,    // [64][512]
    float* __restrict__ c,             // [64][512] in/out (thread-private elem)
    float* __restrict__ h_out) {       // [64][512]
  __shared__ float hs[64][65];
  __shared__ float pg[64][2][2];
  int tid = threadIdx.x;
  int b = tid & 63, w = tid >> 6;
  int hl = w & 1;
  int hidx = blockIdx.x * 2 + hl;
  int gpair = w >> 1;
  const float* wa = W_hh + (size_t)((gpair * 2 + 0) * HD_ + hidx) * HD_;
  const float* wb = W_hh + (size_t)((gpair * 2 + 1) * HD_ + hidx) * HD_;
  float acca = 0.f, accb = 0.f;

  for (int k0 = 0; k0 < HD_; k0 += 64) {
    __syncthreads();
    {
      int r = tid >> 2;            // 0..63
      int ks = (tid & 3) * 16;
      const float* hp = h_in + r * HD_ + k0 + ks;
      float4 v0 = *(const float4*)(hp + 0);
      float4 v1 = *(const float4*)(hp + 4);
      float4 v2 = *(const float4*)(hp + 8);
      float4 v3 = *(const float4*)(hp + 12);
      hs[ks +  0][r] = v0.x; hs[ks +  1][r] = v0.y; hs[ks +  2][r] = v0.z; hs[ks +  3][r] = v0.w;
      hs[ks +  4][r] = v1.x; hs[ks +  5][r] = v1.y; hs[ks +  6][r] = v1.z; hs[ks +  7][r] = v1.w;
      hs[ks +  8][r] = v2.x; hs[ks +  9][r] = v2.y; hs[ks + 10][r] = v2.z; hs[ks + 11][r] = v2.w;
      hs[ks + 12][r] = v3.x; hs[ks + 13][r] = v3.y; hs[ks + 14][r] = v3.z; hs[ks + 15][r] = v3.w;
    }
    __syncthreads();
#pragma unroll
    for (int kk = 0; kk < 64; kk += 4) {
      int k = k0 + kk;
      float4 a4 = *(const float4*)(wa + k);
      float4 b4 = *(const float4*)(wb + k);
      float h0 = hs[kk + 0][b], h1 = hs[kk + 1][b];
      float h2 = hs[kk + 2][b], h3 = hs[kk + 3][b];
      acca += h0 * a4.x + h1 * a4.y + h2 * a4.z + h3 * a4.w;
      accb += h0 * b4.x + h1 * b4.y + h2 * b4.z + h3 * b4.w;
    }
  }

  if (gpair == 1) { pg[b][hl][0] = acca; pg[b][hl][1] = accb; }
  __syncthreads();
  if (gpair == 0) {
    const float* gp = gpre_t + (size_t)b * G4_;
    float gi = acca + gp[0 * HD_ + hidx];
    float gf = accb + gp[1 * HD_ + hidx];
    float gg = pg[b][hl][0] + gp[2 * HD_ + hidx];
    float go = pg[b][hl][1] + gp[3 * HD_ + hidx];
    float cn = sigmoidf_(gf) * c[(size_t)b * HD_ + hidx] + sigmoidf_(gi) * tanhf(gg);
    c[(size_t)b * HD_ + hidx] = cn;
    h_out[(size_t)b * HD_ + hidx] = sigmoidf_(go) * tanhf(cn);
  }
}

// ---------------------------------------------------------------------------
// bf16 MFMA GEMM: C[M,N] = A[M,K](bf16) @ Bw[N,K](bf16)^T + bias, fp32 out.
// Block 256 thr = 4 waves in 2x2; block tile 128x128; wave tile 64x64 via
// 4x4 grid of 16x16x32 MFMAs. Fragments loaded straight from global (L2).
// A-frag: lane L -> row m0+mt*16+(L&15), k = k0+(L>>4)*8 .. +8  (16B).
// D: col = lane&15 (n), row = (lane>>4)*4 + reg (m).   [verified layouts]
// ---------------------------------------------------------------------------
__global__ __launch_bounds__(256) void k_gemm_mfma(
    const unsigned short* __restrict__ A,   // [M][K] bf16
    const unsigned short* __restrict__ Bw,  // [N][K] bf16
    const float* __restrict__ bias,
    float* __restrict__ C, int M, int Nn, int K) {
  int wave = threadIdx.x >> 6, lane = threadIdx.x & 63;
  int wm = wave & 1, wn = wave >> 1;
  int m0 = blockIdx.y * 128 + wm * 64;
  int n0 = blockIdx.x * 128 + wn * 64;
  int l15 = lane & 15, quad = lane >> 4;

  f32x4 acc[4][4];
#pragma unroll
  for (int i = 0; i < 4; ++i)
#pragma unroll
    for (int j = 0; j < 4; ++j) acc[i][j] = (f32x4){0.f, 0.f, 0.f, 0.f};

  for (int k0 = 0; k0 < K; k0 += 32) {
    bf16x8 af[4], bf[4];
#pragma unroll
    for (int mt = 0; mt < 4; ++mt)
      af[mt] = *(const bf16x8*)(A + (size_t)(m0 + mt * 16 + l15) * K + k0 + quad * 8);
#pragma unroll
    for (int nt = 0; nt < 4; ++nt) {
      int n = n0 + nt * 16 + l15;
      if (n >= Nn) n = Nn - 1;
      bf[nt] = *(const bf16x8*)(Bw + (size_t)n * K + k0 + quad * 8);
    }
#pragma unroll
    for (int mt = 0; mt < 4; ++mt)
#pragma unroll
      for (int nt = 0; nt < 4; ++nt)
        acc[mt][nt] = __builtin_amdgcn_mfma_f32_16x16x32_bf16(af[mt], bf[nt], acc[mt][nt], 0, 0, 0);
  }

#pragma unroll
  for (int nt = 0; nt < 4; ++nt) {
    int n = n0 + nt * 16 + l15;
    if (n < Nn) {
      float bb = bias[n];
#pragma unroll
      for (int mt = 0; mt < 4; ++mt) {
        int mbase = m0 + mt * 16 + quad * 4;
#pragma unroll
        for (int r = 0; r < 4; ++r)
          C[(size_t)(mbase + r) * Nn + n] = acc[mt][nt][r] + bb;
      }
    }
  }
}

// ---------------------------------------------------------------------------
// Fused log_softmax + softmax per row of logits [1280][10000] (in place for
// softmax; log_softmax to out1).
// ---------------------------------------------------------------------------
__global__ void k_softmax(float* __restrict__ logits, float* __restrict__ out1) {
  __shared__ float red[8];
  int row = blockIdx.x, tid = threadIdx.x;
  int lane = tid & 63, wid = tid >> 6;
  float* lr = logits + (size_t)row * V_;
  float* o1 = out1 + (size_t)row * V_;
  const int NV4 = V_ / 4;  // 2500

  float m = -1e30f;
  for (int i = tid; i < NV4; i += 256) {
    float4 v = ((const float4*)lr)[i];
    m = fmaxf(m, fmaxf(fmaxf(v.x, v.y), fmaxf(v.z, v.w)));
  }
#pragma unroll
  for (int off = 32; off > 0; off >>= 1) m = fmaxf(m, __shfl_down(m, off, 64));
  if (lane == 0) red[4 + wid] = m;
  __syncthreads();
  m = fmaxf(fmaxf(red[4], red[5]), fmaxf(red[6], red[7]));

  float s = 0.f;
  for (int i = tid; i < NV4; i += 256) {
    float4 v = ((const float4*)lr)[i];
    s += __expf(v.x - m) + __expf(v.y - m) + __expf(v.z - m) + __expf(v.w - m);
  }
#pragma unroll
  for (int off = 32; off > 0; off >>= 1) s += __shfl_down(s, off, 64);
  if (lane == 0) red[wid] = s;
  __syncthreads();
  s = red[0] + red[1] + red[2] + red[3];
  float ls = __logf(s), inv = 1.f / s;

  for (int i = tid; i < NV4; i += 256) {
    float4 v = ((const float4*)lr)[i];
    float4 a, bb;
    a.x = v.x - m - ls; a.y = v.y - m - ls; a.z = v.z - m - ls; a.w = v.w - m - ls;
    bb.x = __expf(v.x - m) * inv; bb.y = __expf(v.y - m) * inv;
    bb.z = __expf(v.z - m) * inv; bb.w = __expf(v.w - m) * inv;
    ((float4*)o1)[i] = a;
    ((float4*)lr)[i] = bb;
  }
}

// ---------------------------------------------------------------------------
extern "C" void kernel_launch(void* const* d_in, const int* in_sizes, int n_in,
                              void* d_out, int out_size, void* d_ws, size_t ws_size,
                              hipStream_t stream) {
  const float* features = (const float*)d_in[0];
  const int*   captions = (const int*)d_in[1];
  const float* W_init_h = (const float*)d_in[2];
  const float* W_init_c = (const float*)d_in[3];
  const float* W_av     = (const float*)d_in[4];
  // d_in[5] b_av, d_in[6] W_ah, d_in[7] b_ah: cancel inside softmax over n.
  const float* embed    = (const float*)d_in[8];
  const float* W_ih     = (const float*)d_in[9];
  const float* W_hh     = (const float*)d_in[10];
  const float* b_ih     = (const float*)d_in[11];
  const float* b_hh     = (const float*)d_in[12];
  const float* W_out    = (const float*)d_in[13];
  const float* b_out    = (const float*)d_in[14];

  float* ws    = (float*)d_ws;
  float* fmean = ws;                       // 64*512
  float* ctx   = fmean + B_ * VD_;         // 64*512
  float* hbuf  = ctx + B_ * VD_;           // 64*512  (h0)
  float* cbuf  = hbuf + B_ * HD_;          // 64*512  (c, in-place)
  float* gctx  = cbuf + B_ * HD_;          // 64*2048
  float* bsum  = gctx + (size_t)B_ * G4_;  // 2048
  float* gpre  = bsum + G4_;               // 20*64*2048
  float* hall  = gpre + (size_t)T_ * B_ * G4_;          // 20*64*512
  unsigned short* wout_bf = (unsigned short*)(hall + (size_t)T_ * B_ * HD_); // 10000*512
  unsigned short* hall_bf = wout_bf + (size_t)V_ * HD_;                      // 1280*512
  // total ws: ~14.2 MB fp32 + ~11.6 MB bf16 = ~25.8 MB

  float* out1   = (float*)d_out;                      // log_softmax [T,B,V]
  float* logits = out1 + (size_t)T_ * B_ * V_;        // softmax slot = scratch

  k_attn_ctx<<<B_, 256, 0, stream>>>(features, W_av, fmean, ctx);
  k_bsum<<<G4_ / 256, 256, 0, stream>>>(b_ih, b_hh, bsum);
  k_cast4<<<(V_ * HD_ / 4 + 255) / 256, 256, 0, stream>>>(W_out, wout_bf, V_ * HD_ / 4);

  // h0 = fmean @ W_init_h^T ; c0 = fmean @ W_init_c^T
  k_gemm_bt<<<dim3(HD_ / 64, B_ / 64), 256, 0, stream>>>(
      fmean, VD_, W_init_h, VD_, hbuf, HD_, HD_, VD_, nullptr);
  k_gemm_bt<<<dim3(HD_ / 64, B_ / 64), 256, 0, stream>>>(
      fmean, VD_, W_init_c, VD_, cbuf, HD_, HD_, VD_, nullptr);

  // gctx = ctx @ W_ih[:, :VD]^T + (b_ih + b_hh)
  k_gemm_bt<<<dim3(G4_ / 64, B_ / 64), 256, 0, stream>>>(
      ctx, VD_, W_ih, VD_ + ED_, gctx, G4_, G4_, VD_, bsum);

  // gpre[t*64+b, :] = embed[captions[b,t]] @ W_ih[:, VD:]^T + gctx[b, :]
  k_gemm_emb<<<dim3(G4_ / 64, (T_ * B_) / 64), 256, 0, stream>>>(
      embed, captions, W_ih + VD_, VD_ + ED_, gctx, gpre);

  // sequential LSTM (h ping-pongs through hall; c in place, thread-private)
  for (int t = 0; t < T_; ++t) {
    const float* h_in = (t == 0) ? hbuf : (hall + (size_t)(t - 1) * B_ * HD_);
    k_step<<<HD_ / 2, 256, 0, stream>>>(
        W_hh, gpre + (size_t)t * B_ * G4_, h_in, cbuf, hall + (size_t)t * B_ * HD_);
  }

  // logits = hall @ W_out^T + b_out via bf16 MFMA (fp32 accumulate)
  k_cast4<<<(T_ * B_ * HD_ / 4 + 255) / 256, 256, 0, stream>>>(
      hall, hall_bf, T_ * B_ * HD_ / 4);
  k_gemm_mfma<<<dim3((V_ + 127) / 128, (T_ * B_) / 128), 256, 0, stream>>>(
      hall_bf, wout_bf, b_out, logits, T_ * B_, V_, HD_);

  // out1 = log_softmax, logits slot overwritten with softmax
  k_softmax<<<T_ * B_, 256, 0, stream>>>(logits, out1);
}